// Round 2
// baseline (743.145 us; speedup 1.0000x reference)
//
#include <hip/hip_runtime.h>

#define B   16384
#define F_S 26
#define F_D 13
#define V   100000
#define D   64

// One wave (64 lanes) per batch row. lane == latent dim d.
// Dominant cost: 26 gathers of 256B each from the 665MB emb_v table.
__global__ __launch_bounds__(256) void fm_kernel(
    const int*   __restrict__ sparse_idx,    // [B, F_S]
    const float* __restrict__ dense,         // [B, F_D]
    const float* __restrict__ emb_lin,       // [F_S, V]
    const float* __restrict__ emb_v,         // [F_S, V, D]
    const float* __restrict__ lin_dense_W,   // [1, F_D]
    const float* __restrict__ lin_dense_b,   // [1]
    const float* __restrict__ dense_arch_W,  // [D, F_D]
    const float* __restrict__ dense_arch_b,  // [D]
    const float* __restrict__ bias,          // [1, 1]
    float*       __restrict__ out)           // [B]
{
    const int wave = threadIdx.x >> 6;
    const int lane = threadIdx.x & 63;
    const int row  = blockIdx.x * 4 + wave;   // blockDim.x == 256 -> 4 waves

    // --- load this row's sparse indices: lane f (<26) holds idx[f] ---
    int myidx = 0;
    if (lane < F_S) myidx = sparse_idx[row * F_S + lane];

    // --- broadcast dense features (13 same-address loads -> L1 broadcast) ---
    float dvals[F_D];
#pragma unroll
    for (int j = 0; j < F_D; ++j) dvals[j] = dense[row * F_D + j];

    // --- v_d[lane] = dense_arch_W[lane,:] . dense[row,:] + b[lane] ---
    float vd = dense_arch_b[lane];
#pragma unroll
    for (int j = 0; j < F_D; ++j)
        vd = fmaf(dense_arch_W[lane * F_D + j], dvals[j], vd);

    float S  = vd;        // running sum over the F_S+1 vectors, dim=lane
    float sq = vd * vd;   // running sum of squares, dim=lane

    // --- 26 embedding gathers; fully unrolled so all loads are in flight ---
#pragma unroll
    for (int f = 0; f < F_S; ++f) {
        int idxf = __shfl(myidx, f);
        float val = emb_v[((size_t)f * V + (size_t)idxf) * D + lane];
        S  += val;
        sq  = fmaf(val, val, sq);
    }

    // --- per-lane partial of the scalar output ---
    float part = 0.5f * (S * S - sq);          // second-order term, dim=lane
    if (lane < F_D) part = fmaf(dvals[lane], lin_dense_W[lane], part);
    if (lane < F_S) part += emb_lin[lane * V + myidx];

    // --- 64-lane butterfly reduction ---
#pragma unroll
    for (int off = 32; off > 0; off >>= 1)
        part += __shfl_xor(part, off);

    if (lane == 0)
        out[row] = part + lin_dense_b[0] + bias[0];
}

extern "C" void kernel_launch(void* const* d_in, const int* in_sizes, int n_in,
                              void* d_out, int out_size, void* d_ws, size_t ws_size,
                              hipStream_t stream) {
    const int*   sparse_idx   = (const int*)  d_in[0];
    const float* dense        = (const float*)d_in[1];
    const float* emb_lin      = (const float*)d_in[2];
    const float* emb_v        = (const float*)d_in[3];
    const float* lin_dense_W  = (const float*)d_in[4];
    const float* lin_dense_b  = (const float*)d_in[5];
    const float* dense_arch_W = (const float*)d_in[6];
    const float* dense_arch_b = (const float*)d_in[7];
    const float* bias         = (const float*)d_in[8];
    float*       out          = (float*)d_out;

    // 4 waves per 256-thread block, one wave per row.
    fm_kernel<<<dim3(B / 4), dim3(256), 0, stream>>>(
        sparse_idx, dense, emb_lin, emb_v,
        lin_dense_W, lin_dense_b, dense_arch_W, dense_arch_b, bias, out);
}